// Round 4
// baseline (658.857 us; speedup 1.0000x reference)
//
#include <hip/hip_runtime.h>
#include <stdint.h>

#define BS 128
#define SL 512
#define HD 1024
#define DD 512
#define M_TOT (BS*SL)   // 65536

typedef __attribute__((ext_vector_type(8))) short short8;
typedef __attribute__((ext_vector_type(4))) float f32x4;

__device__ __forceinline__ float fast_tanh(float x) {
    float e = __expf(2.0f * x);
    return 1.0f - 2.0f / (e + 1.0f);
}

// ---------------- pack Wq into bf16 hi/lo, MFMA-frag order ----------------
// Tile (nb 0..3, ks 0..31): 16KB block = 4096 hi halves then 4096 lo halves.
// n = nb*128+cg*16+(l&15), k = ks*32+(l>>4)*8+j -> half index (cg*64+l)*8+j.
__global__ void pack_wq_kernel(const float* __restrict__ Wq,
                               unsigned short* __restrict__ P) {
    int t = blockIdx.x * 256 + threadIdx.x;   // 0..65535
    int d  = t >> 7;           // 0..511
    int h0 = (t & 127) << 3;   // 0..1016
    const float* src = Wq + (size_t)d * HD + h0;
    union { unsigned short s[8]; uint4 v; } a, b;
#pragma unroll
    for (int j = 0; j < 8; ++j) {
        union { float f; unsigned u; } v; v.f = src[j];
        unsigned hi = v.u & 0xFFFF0000u;
        float lo = v.f - __uint_as_float(hi);
        // round lo to nearest bf16
        unsigned lu = __float_as_uint(lo);
        lu = lu + 0x7FFFu + ((lu >> 16) & 1u);
        a.s[j] = (unsigned short)(hi >> 16);
        b.s[j] = (unsigned short)(lu >> 16);
    }
    int nb = d >> 7, cg = (d >> 4) & 7, lr = d & 15;
    int ks = h0 >> 5, q = (h0 >> 3) & 3;
    int l = q * 16 + lr;
    size_t base = (size_t)(nb * 32 + ks) * 8192 + (size_t)(cg * 64 + l) * 8;
    *(uint4*)(P + base)        = a.v;
    *(uint4*)(P + base + 4096) = b.v;
}

// ---------------- phase 1: partial scores, LDS-free MFMA ----------------
// 128x128 block tile, 4 waves (2x2), each 64x64 (4x4 of 16x16x32 bf16).
// 3-term bf16 split: xh*Wh + xl*Wh + xh*Wl. No LDS, no barriers: A-frags
// loaded per-lane from x (L2), B-frags coalesced from frag-ordered packW.
// Each wave stores its 64-col partial score to its own slice (no atomics).
__launch_bounds__(256, 3)
__global__ void score_kernel(const float* __restrict__ x,
                             const unsigned short* __restrict__ packW,
                             const float* __restrict__ bq,
                             const float* __restrict__ vq,
                             float* __restrict__ scorep) {
    const int bid = blockIdx.x;
    const int xcd = bid & 7;
    const int slot = bid >> 3;              // 0..255
    const int nb = slot & 3;                // N tile of 128
    const int m0 = (xcd + ((slot >> 2) << 3)) << 7;  // row tile * 128

    const int t = threadIdx.x;
    const int l = t & 63;
    const int w = t >> 6;
    const int wm = w & 1, wn = w >> 1;      // 2x2 wave grid

    const int lr = l & 15;                  // A row within 16
    const int lk = l >> 4;                  // k-group (8 elems)

    f32x4 acc[4][4];
#pragma unroll
    for (int i = 0; i < 4; ++i)
#pragma unroll
        for (int j = 0; j < 4; ++j)
            acc[i][j] = (f32x4){0.f, 0.f, 0.f, 0.f};

    const float* xb = x + (size_t)(m0 + wm * 64 + lr) * HD + lk * 8;
    const unsigned short* wb = packW + (size_t)nb * 32 * 8192 + (wn * 4) * 512 + l * 8;

    for (int ks = 0; ks < 32; ++ks) {
        // B fragments: contiguous 16B per lane, 1KB per wave-instr
        short8 bh[4], bl[4];
        const unsigned short* wp = wb + ks * 8192;
#pragma unroll
        for (int j = 0; j < 4; ++j) {
            bh[j] = *(const short8*)(wp + j * 512);
            bl[j] = *(const short8*)(wp + j * 512 + 4096);
        }
        const float* xk = xb + ks * 32;
#pragma unroll
        for (int i = 0; i < 4; ++i) {
            float4 v0 = *(const float4*)(xk + (size_t)i * 16 * HD);
            float4 v1 = *(const float4*)(xk + (size_t)i * 16 * HD + 4);
            unsigned a[8] = {
                __float_as_uint(v0.x), __float_as_uint(v0.y),
                __float_as_uint(v0.z), __float_as_uint(v0.w),
                __float_as_uint(v1.x), __float_as_uint(v1.y),
                __float_as_uint(v1.z), __float_as_uint(v1.w)};
            union { unsigned u[4]; short8 v; } H, L;
#pragma unroll
            for (int p = 0; p < 4; ++p) {
                unsigned e0 = a[2 * p], e1 = a[2 * p + 1];
                float l0 = __uint_as_float(e0) - __uint_as_float(e0 & 0xFFFF0000u);
                float l1 = __uint_as_float(e1) - __uint_as_float(e1 & 0xFFFF0000u);
                H.u[p] = __builtin_amdgcn_perm(e1, e0, 0x07060302u);
                L.u[p] = __builtin_amdgcn_perm(__float_as_uint(l1),
                                               __float_as_uint(l0), 0x07060302u);
            }
#pragma unroll
            for (int j = 0; j < 4; ++j) {
                acc[i][j] = __builtin_amdgcn_mfma_f32_16x16x32_bf16(H.v, bh[j], acc[i][j], 0, 0, 0);
                acc[i][j] = __builtin_amdgcn_mfma_f32_16x16x32_bf16(L.v, bh[j], acc[i][j], 0, 0, 0);
                acc[i][j] = __builtin_amdgcn_mfma_f32_16x16x32_bf16(H.v, bl[j], acc[i][j], 0, 0, 0);
            }
        }
    }

    // ---- epilogue: + bq, tanh, *vq, reduce cols, plain store ----
    // C/D layout: col = lane&15, row = (lane>>4)*4 + reg
    int q = l >> 4, c = l & 15;
    float* myslice = scorep + (size_t)(nb * 2 + wn) * M_TOT;
#pragma unroll
    for (int i = 0; i < 4; ++i) {
        float rs[4] = {0.f, 0.f, 0.f, 0.f};
#pragma unroll
        for (int j = 0; j < 4; ++j) {
            int n = nb * 128 + wn * 64 + j * 16 + c;
            float bqv = bq[n], vqv = vq[n];
            f32x4 a4 = acc[i][j];
#pragma unroll
            for (int r = 0; r < 4; ++r)
                rs[r] += fast_tanh(a4[r] + bqv) * vqv;
        }
#pragma unroll
        for (int r = 0; r < 4; ++r) {
            float v = rs[r];
            v += __shfl_xor(v, 1);
            v += __shfl_xor(v, 2);
            v += __shfl_xor(v, 4);
            v += __shfl_xor(v, 8);
            if (c == 0)
                myslice[m0 + wm * 64 + i * 16 + q * 4 + r] = v;
        }
    }
}

// ---------------- phase 2: fused softmax + weighted sum ----------------
// Block (b, hs): computes row-b masked softmax (redundantly per hs), then
// out[b, hs*256 .. +256] = sum_s w[s] * x[b,s,hs*256..]. Waves split the
// s-range into 4 chunks of 128; LDS reduce at the end.
__global__ void out_kernel(const float* __restrict__ x,
                           const float* __restrict__ scorep,
                           const void* __restrict__ maskp,
                           float* __restrict__ out) {
    __shared__ float wsh[SL];       // softmax weights
    __shared__ float psh[4 * 256];  // per-wave partials
    __shared__ float red[8];
    __shared__ int flags[4];

    const int b = blockIdx.x, hs = blockIdx.y, t = threadIdx.x;
    const int w = t >> 6, l = t & 63;

    // ---- mask dtype detection (first 1024 words; >1 => byte-packed bool) --
    const unsigned* mw = (const unsigned*)maskp;
    int bad = (mw[t] > 1u) || (mw[t + 256] > 1u) ||
              (mw[t + 512] > 1u) || (mw[t + 768] > 1u);
    bad = __any(bad);
    if (l == 0) flags[w] = bad;
    __syncthreads();
    const bool u8 = (flags[0] | flags[1] | flags[2] | flags[3]) != 0;

    // ---- masked softmax over s=512 (threads t and t+256) ----
    int s0 = t, s1 = t + 256;
    float sc0 = 0.f, sc1 = 0.f;
#pragma unroll
    for (int p = 0; p < 8; ++p) {
        sc0 += scorep[(size_t)p * M_TOT + b * SL + s0];
        sc1 += scorep[(size_t)p * M_TOT + b * SL + s1];
    }
    bool mk0, mk1;
    if (u8) {
        mk0 = ((const unsigned char*)maskp)[b * SL + s0] != 0;
        mk1 = ((const unsigned char*)maskp)[b * SL + s1] != 0;
    } else {
        mk0 = ((const int*)maskp)[b * SL + s0] != 0;
        mk1 = ((const int*)maskp)[b * SL + s1] != 0;
    }
    float v0 = mk0 ? -1000000.0f : sc0;
    float v1 = mk1 ? -1000000.0f : sc1;
    float mx = fmaxf(v0, v1);
    for (int d = 1; d < 64; d <<= 1) mx = fmaxf(mx, __shfl_xor(mx, d));
    if (l == 0) red[w] = mx;
    __syncthreads();
    mx = fmaxf(fmaxf(red[0], red[1]), fmaxf(red[2], red[3]));
    float e0 = expf(v0 - mx), e1 = expf(v1 - mx);
    float sm = e0 + e1;
    for (int d = 1; d < 64; d <<= 1) sm += __shfl_xor(sm, d);
    if (l == 0) red[4 + w] = sm;
    __syncthreads();
    sm = red[4] + red[5] + red[6] + red[7];
    float inv = 1.0f / sm;
    wsh[s0] = e0 * inv;
    wsh[s1] = e1 * inv;
    __syncthreads();

    // ---- weighted sum: wave w covers s in [w*128, (w+1)*128) ----
    const float* xp = x + ((size_t)b * SL + w * 128) * HD + hs * 256 + l * 4;
    float ax = 0.f, ay = 0.f, az = 0.f, aw = 0.f;
#pragma unroll 8
    for (int s = 0; s < 128; ++s) {
        float wv = wsh[w * 128 + s];
        float4 v = *(const float4*)(xp + (size_t)s * HD);
        ax += wv * v.x; ay += wv * v.y; az += wv * v.z; aw += wv * v.w;
    }
    psh[w * 256 + l * 4 + 0] = ax;
    psh[w * 256 + l * 4 + 1] = ay;
    psh[w * 256 + l * 4 + 2] = az;
    psh[w * 256 + l * 4 + 3] = aw;
    __syncthreads();

    // ---- final reduce: thread t -> column hs*256 + t ----
    float r0 = psh[t] + psh[256 + t] + psh[512 + t] + psh[768 + t];
    out[(size_t)b * HD + hs * 256 + t] = r0;
}

extern "C" void kernel_launch(void* const* d_in, const int* in_sizes, int n_in,
                              void* d_out, int out_size, void* d_ws, size_t ws_size,
                              hipStream_t stream) {
    const float* x  = (const float*)d_in[0];
    const void* mask = d_in[1];
    const float* Wq = (const float*)d_in[2];
    const float* bq = (const float*)d_in[3];
    const float* vq = (const float*)d_in[4];
    float* out = (float*)d_out;

    char* ws = (char*)d_ws;
    unsigned short* packW = (unsigned short*)ws;          // 2 MB
    float* scorep = (float*)(ws + (2u << 20));            // 8 * 256 KB = 2 MB

    pack_wq_kernel<<<256, 256, 0, stream>>>(Wq, packW);
    score_kernel<<<2048, 256, 0, stream>>>(x, packW, bq, vq, scorep);
    out_kernel<<<dim3(BS, 4), 256, 0, stream>>>(x, scorep, mask, out);
}